// Round 1
// baseline (357.299 us; speedup 1.0000x reference)
//
#include <hip/hip_runtime.h>

#define HIDDEN   128
#define TPB      1024
#define PPT      20              // paths/thread: 60 ids + 20 acc ~= 100 VGPR < 128 cap
#define CN       51200           // nodes per plane-chunk (single l) staged in LDS
#define CN2      102400          // bytes per full plane-chunk (CN * 2)
#define DUMMY2   102400          // byte offset of the zeroed dummy slot
#define UNITS    (CN2 / 1024)    // 100 x 1KB wave-units per full chunk

typedef int   v4i __attribute__((ext_vector_type(4)));
typedef float v4f __attribute__((ext_vector_type(4)));
typedef unsigned short u16;
typedef unsigned int   u32;

static __device__ __forceinline__ u16 f32_to_f16_bits(float x) {
    union { _Float16 h; u16 u; } cv;
    cv.h = (_Float16)x;
    return cv.u;
}

// Async global->LDS DMA, 16 B per lane: lane i's 16 B from its own global
// address land at (wave-uniform lds base) + i*16.
static __device__ __forceinline__ void gload_lds16(const void* gp, void* lp) {
    __builtin_amdgcn_global_load_lds(
        (const __attribute__((address_space(1))) unsigned int*)gp,
        (__attribute__((address_space(3))) unsigned int*)lp,
        16, 0, 0);
}

// Kernel 1: f16 projection table in PLANE-MAJOR layout:
//   proj_h[l * n_nodes + node]  (3 planes of n_nodes f16 each, 600000 B total).
// One wave per node. Total table footprint (incl. fill overread) <= 614400 B,
// identical to the previous chunked layout's workspace usage.
__global__ __launch_bounds__(256) void proj_kernel(
    const float* __restrict__ feat,   // (n_nodes, 128)
    const float* __restrict__ W,      // (3, 1, 128)
    u16* __restrict__ proj_h,         // 3 * n_nodes f16, plane-major
    int n_nodes)
{
    int gtid = blockIdx.x * blockDim.x + threadIdx.x;
    int node = gtid >> 6;
    int lane = threadIdx.x & 63;
    if (node >= n_nodes) return;

    const float2* f2 = (const float2*)(feat + (size_t)node * HIDDEN);
    const float2* w2 = (const float2*)W;

    float2 f   = f2[lane];
    float2 w0  = w2[lane];           // W[0]
    float2 w1  = w2[64 + lane];      // W[1]
    float2 wv2 = w2[128 + lane];     // W[2]

    float s0 = f.x * w0.x  + f.y * w0.y;
    float s1 = f.x * w1.x  + f.y * w1.y;
    float s2 = f.x * wv2.x + f.y * wv2.y;

    #pragma unroll
    for (int off = 32; off > 0; off >>= 1) {
        s0 += __shfl_xor(s0, off, 64);
        s1 += __shfl_xor(s1, off, 64);
        s2 += __shfl_xor(s2, off, 64);
    }

    if (lane == 0) {
        u16* base = proj_h + node;
        base[0]                   = f32_to_f16_bits(s0);
        base[n_nodes]             = f32_to_f16_bits(s1);
        base[2 * (size_t)n_nodes] = f32_to_f16_bits(s2);
    }
}

// Kernel 2: plane-split chunk passes. Each pass stages CN nodes of ONE plane l
// (100 KiB) in LDS; a path element (p,l) is only scanned during its own l's
// passes -> 2 scans/element (vs 4 with l-interleaved chunks), 6 VALU/attempt.
// 20 paths/thread, 512 blocks (2/CU) -> table fill traffic 307 MB (was 768).
// Grid padded to a multiple of 256 blocks; overrun threads clamp loads, skip
// stores, and run all barriers.
__global__ __launch_bounds__(TPB, 4) void score_kernel(
    const int* __restrict__ paths,    // (n_paths, 3) int32
    const u16* __restrict__ proj_h,   // plane-major f16 table
    float* __restrict__ out,          // (n_paths,)
    int n_threads, int n_nodes, int nh)
{
    extern __shared__ u16 lds[];              // CN2 bytes + 4 (dummy)
    char* ldsb = (char*)lds;

    int t    = blockIdx.x * TPB + threadIdx.x;
    int tl   = t < n_threads ? t : n_threads - 1;  // clamp: uniform control flow
    int wid  = threadIdx.x >> 6;
    int lane = threadIdx.x & 63;

    // 20 paths = 60 ids = 15 int4 loads; ids stored pre-doubled (byte offsets,
    // sign preserved: -1 -> -2).
    int id2[3 * PPT];
    const v4i* p4 = (const v4i*)paths;
    #pragma unroll
    for (int i = 0; i < 3 * PPT / 4; ++i) {
        v4i v = __builtin_nontemporal_load(p4 + (size_t)tl * (3 * PPT / 4) + i);
        id2[4*i+0] = v.x << 1; id2[4*i+1] = v.y << 1;
        id2[4*i+2] = v.z << 1; id2[4*i+3] = v.w << 1;
    }

    if (threadIdx.x == 0) lds[DUMMY2 / 2] = 0;   // visible after first barrier

    float acc[PPT];
    #pragma unroll
    for (int p = 0; p < PPT; ++p) acc[p] = 0.0f;

    const unsigned char* tab = (const unsigned char*)proj_h;
    int plane_b = 2 * n_nodes;                   // bytes per plane (200000)

    for (int h = 0; h < nh; ++h) {
        int cb2   = h * CN2;
        int rem_b = plane_b - cb2;               // bytes left in a plane
        int units = rem_b >= CN2 ? UNITS : ((rem_b + 1023) >> 10);

        #pragma unroll
        for (int l = 0; l < 3; ++l) {
            // Async fill: stage plane l, nodes [h*CN, h*CN+CN) — zero waits.
            const unsigned char* src = tab + (size_t)l * plane_b + cb2;
            for (int j = wid; j < units; j += TPB / 64)
                gload_lds16(src + (size_t)j * 1024 + lane * 16,
                            ldsb + j * 1024);
            __syncthreads();                     // drains vmcnt: fill complete

            // One attempt per path: sub, cmp, cndmask, ds_read_u16, cvt, add.
            #pragma unroll
            for (int p = 0; p < PPT; ++p) {
                u32 loc2 = (u32)(id2[3*p + l] - cb2);  // miss/-1 => huge => dummy
                int off  = loc2 < (u32)CN2 ? (int)loc2 : DUMMY2;
                union { u16 u; _Float16 hh; } cv;
                cv.u = *(const u16*)(ldsb + off);
                acc[p] += (float)cv.hh;
            }
            if (h + 1 < nh || l < 2) __syncthreads();  // reads done before next fill
        }
    }

    if (t < n_threads) {
        #pragma unroll
        for (int j = 0; j < PPT / 4; ++j) {
            v4f o;
            #pragma unroll
            for (int q = 0; q < 4; ++q) {
                int p = 4*j + q;
                int cnt = (int)(id2[3*p] >= 0) + (int)(id2[3*p+1] >= 0)
                        + (int)(id2[3*p+2] >= 0);
                float inv = (cnt == 3) ? (1.0f/3.0f) : (cnt == 2 ? 0.5f : 1.0f);
                o[q] = acc[p] * inv;
            }
            __builtin_nontemporal_store(o, ((v4f*)out) + (size_t)t * (PPT/4) + j);
        }
    }
}

extern "C" void kernel_launch(void* const* d_in, const int* in_sizes, int n_in,
                              void* d_out, int out_size, void* d_ws, size_t ws_size,
                              hipStream_t stream) {
    const int*   paths = (const int*)d_in[0];     // (N_PATHS, 3) int32
    const float* feat  = (const float*)d_in[1];   // (N_NODES, 128) f32
    const float* W     = (const float*)d_in[2];   // (3, 1, 128) f32
    float*       out   = (float*)d_out;           // (N_PATHS,) f32

    int n_nodes = in_sizes[1] / HIDDEN;           // 100000
    int n_paths = in_sizes[0] / 3;                // 10000000
    u16* proj_h = (u16*)d_ws;                     // 3 planes * n_nodes f16

    int nh = (n_nodes + CN - 1) / CN;             // 2 plane-chunks per plane
    size_t lds_bytes = (size_t)CN2 + 4;           // 102404

    (void)hipFuncSetAttribute((const void*)score_kernel,
            hipFuncAttributeMaxDynamicSharedMemorySize, (int)lds_bytes);
    (void)hipGetLastError();   // clear any sticky error pre-capture

    // Kernel 1: 1 wave per node, 4 waves per 256-thread block.
    {
        int blocks = (n_nodes + 3) / 4;
        proj_kernel<<<blocks, 256, 0, stream>>>(feat, W, proj_h, n_nodes);
    }

    // Kernel 2: grid padded to a multiple of 256 blocks (exactly 2/CU).
    {
        int n_threads = (n_paths + PPT - 1) / PPT;     // 500,000
        int blocks = (n_threads + TPB - 1) / TPB;      // 489
        blocks = ((blocks + 255) / 256) * 256;         // 512 = 2 * 256
        score_kernel<<<blocks, TPB, lds_bytes, stream>>>(paths, proj_h, out,
                                                         n_threads, n_nodes, nh);
    }
}

// Round 2
// 255.347 us; speedup vs baseline: 1.3993x; 1.3993x over previous
//
#include <hip/hip_runtime.h>

#define HIDDEN   128
#define TPB      1024
#define PPT      12              // paths/thread: 36 ids + 12 acc + temps < 64-reg cap
#define CN       51200           // nodes per plane-chunk (single l) staged in LDS
#define CN2      102400          // bytes per full plane-chunk (CN * 2)
#define DUMMY2   102400          // byte offset of the zeroed dummy slot
#define UNITS    (CN2 / 1024)    // 100 x 1KB wave-units per full chunk

typedef float v4f __attribute__((ext_vector_type(4)));
typedef unsigned short u16;
typedef unsigned int   u32;

static __device__ __forceinline__ u16 f32_to_f16_bits(float x) {
    union { _Float16 h; u16 u; } cv;
    cv.h = (_Float16)x;
    return cv.u;
}

// Async global->LDS DMA, 16 B per lane: lane i's 16 B from its own global
// address land at (wave-uniform lds base) + i*16.
static __device__ __forceinline__ void gload_lds16(const void* gp, void* lp) {
    __builtin_amdgcn_global_load_lds(
        (const __attribute__((address_space(1))) unsigned int*)gp,
        (__attribute__((address_space(3))) unsigned int*)lp,
        16, 0, 0);
}

// Kernel 1: f16 projection table in PLANE-MAJOR layout:
//   proj_h[l * n_nodes + node]  (3 planes of n_nodes f16 each, 600000 B total).
// One wave per node. Fill overread stays < 614400 B of workspace (same budget
// as the original chunked layout).
__global__ __launch_bounds__(256) void proj_kernel(
    const float* __restrict__ feat,   // (n_nodes, 128)
    const float* __restrict__ W,      // (3, 1, 128)
    u16* __restrict__ proj_h,         // 3 * n_nodes f16, plane-major
    int n_nodes)
{
    int gtid = blockIdx.x * blockDim.x + threadIdx.x;
    int node = gtid >> 6;
    int lane = threadIdx.x & 63;
    if (node >= n_nodes) return;

    const float2* f2 = (const float2*)(feat + (size_t)node * HIDDEN);
    const float2* w2 = (const float2*)W;

    float2 f   = f2[lane];
    float2 w0  = w2[lane];           // W[0]
    float2 w1  = w2[64 + lane];      // W[1]
    float2 wv2 = w2[128 + lane];     // W[2]

    float s0 = f.x * w0.x  + f.y * w0.y;
    float s1 = f.x * w1.x  + f.y * w1.y;
    float s2 = f.x * wv2.x + f.y * wv2.y;

    #pragma unroll
    for (int off = 32; off > 0; off >>= 1) {
        s0 += __shfl_xor(s0, off, 64);
        s1 += __shfl_xor(s1, off, 64);
        s2 += __shfl_xor(s2, off, 64);
    }

    if (lane == 0) {
        u16* base = proj_h + node;
        base[0]                   = f32_to_f16_bits(s0);
        base[n_nodes]             = f32_to_f16_bits(s1);
        base[2 * (size_t)n_nodes] = f32_to_f16_bits(s2);
    }
}

// Kernel 2: plane-split chunk passes, BLOCK-STRIDED path assignment.
// Thread tid of block b owns paths  b*TPB*PPT + tid + k*TPB  (k=0..PPT-1):
//   - path loads: 3 dwords/lane, wave-contiguous (768 B per wave per k)
//   - out stores: scalar f32, perfectly coalesced (256 B per wave per k)
// Each pass stages CN nodes of ONE plane l (100 KiB) in LDS; an element (p,l)
// is scanned only in its own plane's 2 passes -> 6*PPT = 72 attempts/thread.
// PPT=12 keeps id2[36]+acc[12] in registers under the 64-VGPR cap (the PPT=20
// variant spilled: VGPR=64 with ~88 live -> 140 MB scratch writes).
__global__ __launch_bounds__(TPB, 4) void score_kernel(
    const int* __restrict__ paths,    // (n_paths, 3) int32
    const u16* __restrict__ proj_h,   // plane-major f16 table
    float* __restrict__ out,          // (n_paths,)
    int n_paths, int n_nodes, int nh)
{
    extern __shared__ u16 lds[];              // CN2 bytes + 4 (dummy)
    char* ldsb = (char*)lds;

    int base = blockIdx.x * (TPB * PPT) + threadIdx.x;
    int wid  = threadIdx.x >> 6;
    int lane = threadIdx.x & 63;

    // ids pre-doubled (byte offsets, sign preserved: -1 -> -2). Static indices.
    int id2[3 * PPT];
    #pragma unroll
    for (int k = 0; k < PPT; ++k) {
        int idx = base + k * TPB;
        int ii  = idx < n_paths ? idx : (n_paths - 1);   // clamp: uniform flow
        const int* pp = paths + (size_t)ii * 3;
        id2[3*k+0] = __builtin_nontemporal_load(pp + 0) << 1;
        id2[3*k+1] = __builtin_nontemporal_load(pp + 1) << 1;
        id2[3*k+2] = __builtin_nontemporal_load(pp + 2) << 1;
    }

    if (threadIdx.x == 0) lds[DUMMY2 / 2] = 0;   // visible after first barrier

    float acc[PPT];
    #pragma unroll
    for (int k = 0; k < PPT; ++k) acc[k] = 0.0f;

    const unsigned char* tab = (const unsigned char*)proj_h;
    int plane_b = 2 * n_nodes;                   // bytes per plane (200000)

    for (int h = 0; h < nh; ++h) {
        int cb2   = h * CN2;
        int rem_b = plane_b - cb2;               // bytes left in a plane
        int units = rem_b >= CN2 ? UNITS : ((rem_b + 1023) >> 10);

        #pragma unroll
        for (int l = 0; l < 3; ++l) {
            // Async fill: stage plane l, nodes [h*CN, h*CN+CN) — zero waits.
            const unsigned char* src = tab + (size_t)l * plane_b + cb2;
            for (int j = wid; j < units; j += TPB / 64)
                gload_lds16(src + (size_t)j * 1024 + lane * 16,
                            ldsb + j * 1024);
            __syncthreads();                     // drains vmcnt: fill complete

            // One attempt per path: sub, cmp, cndmask, ds_read_u16, cvt, add.
            #pragma unroll
            for (int k = 0; k < PPT; ++k) {
                u32 loc2 = (u32)(id2[3*k + l] - cb2);  // miss/-1 => huge => dummy
                int off  = loc2 < (u32)CN2 ? (int)loc2 : DUMMY2;
                union { u16 u; _Float16 hh; } cv;
                cv.u = *(const u16*)(ldsb + off);
                acc[k] += (float)cv.hh;
            }
            if (h + 1 < nh || l < 2) __syncthreads();  // reads done before next fill
        }
    }

    #pragma unroll
    for (int k = 0; k < PPT; ++k) {
        int idx = base + k * TPB;
        if (idx < n_paths) {
            int cnt = (int)(id2[3*k] >= 0) + (int)(id2[3*k+1] >= 0)
                    + (int)(id2[3*k+2] >= 0);
            float inv = (cnt == 3) ? (1.0f/3.0f) : (cnt == 2 ? 0.5f : 1.0f);
            __builtin_nontemporal_store(acc[k] * inv, out + idx);
        }
    }
}

extern "C" void kernel_launch(void* const* d_in, const int* in_sizes, int n_in,
                              void* d_out, int out_size, void* d_ws, size_t ws_size,
                              hipStream_t stream) {
    const int*   paths = (const int*)d_in[0];     // (N_PATHS, 3) int32
    const float* feat  = (const float*)d_in[1];   // (N_NODES, 128) f32
    const float* W     = (const float*)d_in[2];   // (3, 1, 128) f32
    float*       out   = (float*)d_out;           // (N_PATHS,) f32

    int n_nodes = in_sizes[1] / HIDDEN;           // 100000
    int n_paths = in_sizes[0] / 3;                // 10000000
    u16* proj_h = (u16*)d_ws;                     // 3 planes * n_nodes f16

    int nh = (n_nodes + CN - 1) / CN;             // 2 plane-chunks per plane
    size_t lds_bytes = (size_t)CN2 + 4;           // 102404

    (void)hipFuncSetAttribute((const void*)score_kernel,
            hipFuncAttributeMaxDynamicSharedMemorySize, (int)lds_bytes);
    (void)hipGetLastError();   // clear any sticky error pre-capture

    // Kernel 1: 1 wave per node, 4 waves per 256-thread block.
    {
        int blocks = (n_nodes + 3) / 4;
        proj_kernel<<<blocks, 256, 0, stream>>>(feat, W, proj_h, n_nodes);
    }

    // Kernel 2: 814 blocks, 1/CU (LDS-limited) — ~4 rounds of 256.
    {
        int blocks = (n_paths + TPB * PPT - 1) / (TPB * PPT);  // 814
        score_kernel<<<blocks, TPB, lds_bytes, stream>>>(paths, proj_h, out,
                                                         n_paths, n_nodes, nh);
    }
}